// Round 5
// baseline (5118.452 us; speedup 1.0000x reference)
//
#include <hip/hip_runtime.h>
#include <hip/hip_bf16.h>
#include <stdint.h>

typedef __hip_bfloat16 bf16;
typedef __attribute__((ext_vector_type(8))) short short8;
typedef __attribute__((ext_vector_type(4))) float f32x4;
typedef __attribute__((ext_vector_type(4))) unsigned int u32x4;

#define NN 65536
#define DD 512
#define EE 1048576
#define GG 128
#define LL 512

static __device__ __forceinline__ void gld_lds16(const void* g, void* l) {
  __builtin_amdgcn_global_load_lds((const __attribute__((address_space(1))) uint32_t*)g,
                                   (__attribute__((address_space(3))) uint32_t*)l, 16, 0, 0);
}

// ---------------- prep: transpose/cast weights to bf16 ----------------
__global__ __launch_bounds__(256) void k_prep(
    const float* __restrict__ Wc, const float* __restrict__ Wf1, const float* __restrict__ Wf2,
    const float* __restrict__ Wih, const float* __restrict__ Whh,
    bf16* __restrict__ WcT, bf16* __restrict__ Wf1T, bf16* __restrict__ Wf2T,
    bf16* __restrict__ WihB, bf16* __restrict__ WhhB)
{
  const int i = blockIdx.x * 256 + threadIdx.x;
  if (i < 512 * 512) {
    const int k = i >> 9, n = i & 511;
    WcT [n * 512 + k] = __float2bfloat16(Wc [i]);
    Wf1T[n * 512 + k] = __float2bfloat16(Wf1[i]);
    Wf2T[n * 512 + k] = __float2bfloat16(Wf2[i]);
  }
  if (i < 1536 * 512) {
    WihB[i] = __float2bfloat16(Wih[i]);
    WhhB[i] = __float2bfloat16(Whh[i]);
  }
}

// ---------------- cast node features to bf16 (halves gather volume) ----------------
__global__ __launch_bounds__(256) void k_cast(const float* __restrict__ f, bf16* __restrict__ o) {
  const long i = (long)(blockIdx.x * 256 + threadIdx.x) * 4;
  const float4 v = *(const float4*)&f[i];
  union { bf16 b[4]; ushort4 u; } pk;
  pk.b[0] = __float2bfloat16(v.x);
  pk.b[1] = __float2bfloat16(v.y);
  pk.b[2] = __float2bfloat16(v.z);
  pk.b[3] = __float2bfloat16(v.w);
  *(ushort4*)&o[i] = pk.u;
}

// ---------------- CSR build ----------------
__global__ __launch_bounds__(256) void k_deg(const int* __restrict__ dst, int* __restrict__ deg) {
  const int e = blockIdx.x * 256 + threadIdx.x;
  atomicAdd(&deg[dst[e]], 1);
}

// parallel 3-phase exclusive scan of deg[65536]
__global__ __launch_bounds__(1024) void k_scan1(const int* __restrict__ deg,
                                                int* __restrict__ roff, int* __restrict__ partial) {
  __shared__ int sd[1024];
  const int t = threadIdx.x, b = blockIdx.x, i = b * 1024 + t;
  const int v = deg[i];
  sd[t] = v;
  __syncthreads();
  for (int off = 1; off < 1024; off <<= 1) {
    int add = (t >= off) ? sd[t - off] : 0;
    __syncthreads();
    sd[t] += add;
    __syncthreads();
  }
  roff[i] = sd[t] - v;          // exclusive within chunk
  if (t == 1023) partial[b] = sd[t];
}

__global__ __launch_bounds__(64) void k_scan2(const int* __restrict__ partial, int* __restrict__ base) {
  __shared__ int sd[64];
  const int t = threadIdx.x;
  const int v = partial[t];
  sd[t] = v;
  __syncthreads();
  for (int off = 1; off < 64; off <<= 1) {
    int add = (t >= off) ? sd[t - off] : 0;
    __syncthreads();
    sd[t] += add;
    __syncthreads();
  }
  base[t] = sd[t] - v;
  if (t == 63) base[64] = sd[63];
}

__global__ __launch_bounds__(1024) void k_scan3(const int* __restrict__ base,
                                                int* __restrict__ roff, int* __restrict__ cursor) {
  const int b = blockIdx.x, t = threadIdx.x, i = b * 1024 + t;
  const int v = roff[i] + base[b];
  roff[i] = v;
  cursor[i] = v;
  if (i == 0) roff[NN] = base[64];
}

__global__ __launch_bounds__(256) void k_fill(const int* __restrict__ src, const int* __restrict__ dst,
                                              int* __restrict__ cursor, int* __restrict__ csr) {
  const int e = blockIdx.x * 256 + threadIdx.x;
  const int p = atomicAdd(&cursor[dst[e]], 1);
  csr[p] = src[e];
}

// ---------------- mean aggregation (bf16 gather, fp32 accum) ----------------
__global__ __launch_bounds__(128) void k_agg(
    const bf16* __restrict__ featsb, const int* __restrict__ csr,
    const int* __restrict__ roff, bf16* __restrict__ agg)
{
  const int n = blockIdx.x, t = threadIdx.x;
  const int s0 = roff[n], s1 = roff[n + 1];
  float a0 = 0.f, a1 = 0.f, a2 = 0.f, a3 = 0.f;
  for (int i = s0; i < s1; ++i) {
    const int s = csr[i];
    const ushort4 v = *(const ushort4*)&featsb[(long)s * 512 + t * 4];
    bf16 b0, b1, b2, b3;
    *(uint16_t*)&b0 = v.x; *(uint16_t*)&b1 = v.y;
    *(uint16_t*)&b2 = v.z; *(uint16_t*)&b3 = v.w;
    a0 += __bfloat162float(b0); a1 += __bfloat162float(b1);
    a2 += __bfloat162float(b2); a3 += __bfloat162float(b3);
  }
  const float sc = 1.f / fmaxf((float)(s1 - s0), 1.f);
  union { bf16 b[4]; ushort4 u; } pk;
  pk.b[0] = __float2bfloat16(a0 * sc);
  pk.b[1] = __float2bfloat16(a1 * sc);
  pk.b[2] = __float2bfloat16(a2 * sc);
  pk.b[3] = __float2bfloat16(a3 * sc);
  *(ushort4*)&agg[(long)n * 512 + t * 4] = pk.u;
}

// ---------------- bf16 GEMM: C[M,Ncols] = A[M,512] @ Bt[Ncols,512]^T + bias ----------------
template<bool GATHER, bool RELU, bool SCATTER>
__global__ __launch_bounds__(256) void k_gemm(
    const bf16* __restrict__ A, const bf16* __restrict__ Bt,
    const float* __restrict__ bias, const int* __restrict__ gidx,
    bf16* __restrict__ outb, float* __restrict__ outf, int Ncols)
{
  __shared__ bf16 lsA[128 * 64];
  __shared__ bf16 lsB[128 * 64];
  const int t = threadIdx.x;
  const int lane = t & 63, wid = t >> 6;
  const int wr = wid >> 1, wc = wid & 1;
  const int tm = blockIdx.y * 128, tn = blockIdx.x * 128;
  const int col8 = (t & 7) * 8;
  const int rsub = t >> 3;
  const int lc = lane & 15, lk = lane >> 4;

  long arow[4], brow[4];
#pragma unroll
  for (int i = 0; i < 4; ++i) {
    const int r = tm + i * 32 + rsub;
    int ar = r;
    if constexpr (GATHER) ar = gidx[r];
    arow[i] = (long)ar * 512;
    brow[i] = (long)(tn + i * 32 + rsub) * 512;
  }

  f32x4 acc[4][4];
#pragma unroll
  for (int a = 0; a < 4; ++a)
#pragma unroll
    for (int b = 0; b < 4; ++b) acc[a][b] = (f32x4){0.f, 0.f, 0.f, 0.f};

  for (int ks = 0; ks < 8; ++ks) {
    const int k0 = ks * 64;
#pragma unroll
    for (int i = 0; i < 4; ++i) {
      gld_lds16(A  + arow[i] + k0 + col8, &lsA[i * 2048 + t * 8]);
      gld_lds16(Bt + brow[i] + k0 + col8, &lsB[i * 2048 + t * 8]);
    }
    __syncthreads();
#pragma unroll
    for (int kk = 0; kk < 2; ++kk) {
      short8 af[4], bfr[4];
#pragma unroll
      for (int mi = 0; mi < 4; ++mi)
        af[mi] = *(const short8*)&lsA[(wr * 64 + mi * 16 + lc) * 64 + kk * 32 + lk * 8];
#pragma unroll
      for (int ni = 0; ni < 4; ++ni)
        bfr[ni] = *(const short8*)&lsB[(wc * 64 + ni * 16 + lc) * 64 + kk * 32 + lk * 8];
#pragma unroll
      for (int mi = 0; mi < 4; ++mi)
#pragma unroll
        for (int ni = 0; ni < 4; ++ni)
          acc[mi][ni] = __builtin_amdgcn_mfma_f32_16x16x32_bf16(af[mi], bfr[ni], acc[mi][ni], 0, 0, 0);
    }
    __syncthreads();
  }

  float bv[4];
#pragma unroll
  for (int ni = 0; ni < 4; ++ni) bv[ni] = bias[tn + wc * 64 + ni * 16 + lc];

#pragma unroll
  for (int mi = 0; mi < 4; ++mi) {
    const int r0 = tm + wr * 64 + mi * 16 + lk * 4;
#pragma unroll
    for (int j = 0; j < 4; ++j) {
      const int row = r0 + j;
      long orow;
      if constexpr (SCATTER) orow = (long)gidx[row] * 512;
      else                   orow = (long)row * Ncols;
#pragma unroll
      for (int ni = 0; ni < 4; ++ni) {
        float v = acc[mi][ni][j] + bv[ni];
        if constexpr (RELU) v = fmaxf(v, 0.f);
        const int c = tn + wc * 64 + ni * 16 + lc;
        if constexpr (SCATTER) outf[orow + c] = v;
        else                   outb[orow + c] = __float2bfloat16(v);
      }
    }
  }
}

// ---------------- persistent GRU v4: tagged self-validating exchange ----------------
// 64 blocks = 2 jm x 32 jc; 4 waves/block; wave w = chain jm*4+w (16 groups)
// x 16 d-cols (jc). W_hh slice in LDS. Exchange buffer hx[parity][g][d]
// (dwords, 512 KB total -> Infinity-Cache-resident, no write-allocate HBM
// fetches) holds {tag=l+1 <<16 | bf16 h}. The data IS the flag: producers
// fire-and-forget dword stores (no drain, no flag); consumers poll their 128
// exchange dwords with 32 pipelined dwordx4 sc0 sc1 loads + one vmcnt(0) +
// XOR tag-check -> detect in ~1 coherent RTT. Parity reuse is race-free: a
// producer enters step l+1 only after seeing all step-l tags, which implies
// every consumer of step l-1 completed its reads. ys is written via plain
// cached stores (off critical path; kernel boundary publishes it for ff2).
// gi raw-ushort loads are issued before the poll; the poll's vmcnt(0) covers
// them, hiding their HBM latency.
__global__ __launch_bounds__(256, 1) void k_gru4(
    const bf16* __restrict__ Whh, const float* __restrict__ bhh,
    const bf16* __restrict__ gi, uint32_t* __restrict__ hx, bf16* __restrict__ ys)
{
  __shared__ bf16 lsW[48 * 520];
  const int t = threadIdx.x, lane = t & 63, w = t >> 6;
  const int jm = blockIdx.x >> 5, jc = blockIdx.x & 31;
  const int lc = lane & 15, lk = lane >> 4;
  const int chain = jm * 4 + w;        // 0..7
  const int g0 = chain * 16;           // this wave's 16 groups
  const int d = jc * 16 + lc;          // this lane's output column

  // stage Whh slice: rows 0..15 -> gate r, 16..31 -> z, 32..47 -> n (cols jc*16..+16)
#pragma unroll
  for (int it = 0; it < 12; ++it) {
    const int c = it * 256 + t;
    const int row = c >> 6, col = (c & 63) * 8;
    const int e = (row < 16) ? (jc * 16 + row)
                : (row < 32) ? (512 + jc * 16 + row - 16)
                             : (1024 + jc * 16 + row - 32);
    *(uint4*)&lsW[row * 520 + col] = *(const uint4*)&Whh[(long)e * 512 + col];
  }
  __syncthreads();

  const float bR = bhh[d], bZ = bhh[512 + d], bN = bhh[1024 + d];
  float hreg[4] = {0.f, 0.f, 0.f, 0.f};

  // consumer read base: hx[parity][g0+lc][lk*8 + kk*32 ...]
  const uint32_t* pb0 = hx + ((g0 + lc) << 9) + lk * 8;
  // gi per-j bases (advance 1536 elems/step); offsets 0/1024/2048 bytes = gates
  const bf16* gp[4];
  long ysb4[4];
  int hsb[4];
#pragma unroll
  for (int j = 0; j < 4; ++j) {
    const int g = g0 + lk * 4 + j;
    gp[j]   = gi + (long)g * 786432 + d;     // g*512*1536
    ysb4[j] = ((long)g << 18) + d;           // g*512*512
    hsb[j]  = g * 512 + d;
  }

  for (int l = 0; l < 512; ++l) {
    // issue gi raw loads now; the poll's vmcnt(0) will cover their latency
    uint32_t gr[12];
#pragma unroll
    for (int j = 0; j < 4; ++j) {
      asm volatile("global_load_ushort %0, %1, off"             : "=v"(gr[j * 3 + 0]) : "v"(gp[j]) : "memory");
      asm volatile("global_load_ushort %0, %1, off offset:1024" : "=v"(gr[j * 3 + 1]) : "v"(gp[j]) : "memory");
      asm volatile("global_load_ushort %0, %1, off offset:2048" : "=v"(gr[j * 3 + 2]) : "v"(gp[j]) : "memory");
      gp[j] += 1536;
    }

    f32x4 acc[3] = { (f32x4){0.f,0.f,0.f,0.f}, (f32x4){0.f,0.f,0.f,0.f}, (f32x4){0.f,0.f,0.f,0.f} };
    u32x4 hv[32];
    if (l > 0) {
      const uint32_t tagw = (uint32_t)l << 16;       // h_{l-1} carries tag l
      const uint32_t* pb = pb0 + (((l - 1) & 1) << 16);
      int ok;
      do {
#pragma unroll
        for (int kk = 0; kk < 16; ++kk) {
          asm volatile("global_load_dwordx4 %0, %1, off offset:%2 sc0 sc1"
                       : "=v"(hv[kk * 2 + 0]) : "v"(pb), "n"(kk * 128) : "memory");
          asm volatile("global_load_dwordx4 %0, %1, off offset:%2 sc0 sc1"
                       : "=v"(hv[kk * 2 + 1]) : "v"(pb), "n"(kk * 128 + 16) : "memory");
        }
        asm volatile("s_waitcnt vmcnt(0)" ::: "memory");
        __builtin_amdgcn_sched_barrier(0);
        uint32_t bad = 0;
#pragma unroll
        for (int i = 0; i < 32; ++i) {
          bad |= (hv[i][0] ^ tagw); bad |= (hv[i][1] ^ tagw);
          bad |= (hv[i][2] ^ tagw); bad |= (hv[i][3] ^ tagw);
        }
        ok = __all((bad >> 16) == 0);
      } while (!ok);

      // unpack low halves pairwise -> 16 short8 A-frags, MFMA
#pragma unroll
      for (int kk = 0; kk < 16; ++kk) {
        union { uint32_t u[4]; short8 s; } cv;
        cv.u[0] = (hv[kk * 2 + 0][0] & 0xffffu) | (hv[kk * 2 + 0][1] << 16);
        cv.u[1] = (hv[kk * 2 + 0][2] & 0xffffu) | (hv[kk * 2 + 0][3] << 16);
        cv.u[2] = (hv[kk * 2 + 1][0] & 0xffffu) | (hv[kk * 2 + 1][1] << 16);
        cv.u[3] = (hv[kk * 2 + 1][2] & 0xffffu) | (hv[kk * 2 + 1][3] << 16);
#pragma unroll
        for (int gate = 0; gate < 3; ++gate) {
          const short8 bfr = *(const short8*)&lsW[(gate * 16 + lc) * 520 + kk * 32 + lk * 8];
          acc[gate] = __builtin_amdgcn_mfma_f32_16x16x32_bf16(cv.s, bfr, acc[gate], 0, 0, 0);
        }
      }
    } else {
      asm volatile("s_waitcnt vmcnt(0)" ::: "memory");
      __builtin_amdgcn_sched_barrier(0);
    }

    const uint32_t tagw1 = (uint32_t)(l + 1) << 16;
    uint32_t* hw = hx + ((l & 1) << 16);
#pragma unroll
    for (int j = 0; j < 4; ++j) {
      union { uint32_t u; float f; } cu;
      cu.u = gr[j * 3 + 0] << 16;  const float giR = cu.f;
      cu.u = gr[j * 3 + 1] << 16;  const float giZ = cu.f;
      cu.u = gr[j * 3 + 2] << 16;  const float giN = cu.f;
      const float r = 1.f / (1.f + __expf(-(giR + acc[0][j] + bR)));
      const float z = 1.f / (1.f + __expf(-(giZ + acc[1][j] + bZ)));
      const float x2 = giN + r * (acc[2][j] + bN);
      const float ex = __expf(2.f * x2);
      const float n = 1.f - 2.f / (ex + 1.f);          // tanh
      const float hn = (1.f - z) * n + z * hreg[j];
      hreg[j] = hn;
      const bf16 hnb = __float2bfloat16(hn);
      const uint32_t val = tagw1 | (uint32_t)(*(const uint16_t*)&hnb);
      uint32_t* hp = hw + hsb[j];
      asm volatile("global_store_dword %0, %1, off sc0 sc1" :: "v"(hp), "v"(val) : "memory");
      ys[ysb4[j] + ((long)l << 9)] = hnb;              // plain cached store
    }
  }
}

// ---------------- launch ----------------
extern "C" void kernel_launch(void* const* d_in, const int* in_sizes, int n_in,
                              void* d_out, int out_size, void* d_ws, size_t ws_size,
                              hipStream_t stream)
{
  (void)in_sizes; (void)n_in; (void)out_size; (void)ws_size;
  const float* in_feats = (const float*)d_in[0];
  const int*   e_src    = (const int*)d_in[1];
  const int*   e_dst    = (const int*)d_in[2];
  const int*   seq      = (const int*)d_in[3];
  const float* W_conv   = (const float*)d_in[4];
  const float* b_conv   = (const float*)d_in[5];
  const float* W_ff1    = (const float*)d_in[6];
  const float* b_ff1    = (const float*)d_in[7];
  const float* W_ih     = (const float*)d_in[8];
  const float* W_hh     = (const float*)d_in[9];
  const float* b_ih     = (const float*)d_in[10];
  const float* b_hh     = (const float*)d_in[11];
  const float* W_ff2    = (const float*)d_in[12];
  const float* b_ff2    = (const float*)d_in[13];

  uint8_t* ws = (uint8_t*)d_ws;
  int*  deg     = (int*) (ws + 0);
  int*  cursor  = (int*) (ws + 262144u);
  int*  roff    = (int*) (ws + 524288u);
  bf16* WcT     = (bf16*)(ws + 1048576u);
  bf16* Wf1T    = (bf16*)(ws + 1572864u);
  bf16* Wf2T    = (bf16*)(ws + 2097152u);
  bf16* WihB    = (bf16*)(ws + 2621440u);
  bf16* WhhB    = (bf16*)(ws + 4194304u);
  int*  csr     = (int*) (ws + 6291456u);
  int*  partial = (int*) (ws + 10616832u);   // 64 ints
  int*  sbase   = (int*) (ws + 10620928u);   // 65 ints
  uint32_t* hx  = (uint32_t*)(ws + 11534336u); // 2*128*512 dwords = 512 KB tagged exchange
  bf16* med2    = (bf16*)(ws + 16777216u);   // 67MB; reused as ys after gi GEMM
  bf16* ysb     = med2;
  bf16* gib     = (bf16*)(ws + 83886080u);   // 201MB; aggb/med1/featsb live here pre-gi
  bf16* aggb    = (bf16*)(ws + 83886080u);
  bf16* med1    = (bf16*)(ws + 150994944u);  // also featsb (dead before med1 written)
  bf16* featsb  = (bf16*)(ws + 150994944u);

  hipMemsetAsync(deg, 0, NN * 4, stream);
  hipMemsetAsync(hx,  0, 2 * GG * DD * 4, stream);   // tags -> 0 (never a valid step tag)

  k_prep <<<3072, 256, 0, stream>>>(W_conv, W_ff1, W_ff2, W_ih, W_hh, WcT, Wf1T, Wf2T, WihB, WhhB);
  k_cast <<<NN * DD / 1024, 256, 0, stream>>>(in_feats, featsb);
  k_deg  <<<EE / 256, 256, 0, stream>>>(e_dst, deg);
  k_scan1<<<64, 1024, 0, stream>>>(deg, roff, partial);
  k_scan2<<<1, 64, 0, stream>>>(partial, sbase);
  k_scan3<<<64, 1024, 0, stream>>>(sbase, roff, cursor);
  k_fill <<<EE / 256, 256, 0, stream>>>(e_src, e_dst, cursor, csr);
  k_agg  <<<NN, 128, 0, stream>>>(featsb, csr, roff, aggb);

  dim3 g512(4, 512), g1536(12, 512);
  k_gemm<false, false, false><<<g512,  256, 0, stream>>>(aggb, WcT,  b_conv, nullptr, med1, nullptr, 512);
  k_gemm<false, true,  false><<<g512,  256, 0, stream>>>(med1, Wf1T, b_ff1,  nullptr, med2, nullptr, 512);
  k_gemm<true,  false, false><<<g1536, 256, 0, stream>>>(med2, WihB, b_ih,   seq,     gib,  nullptr, 1536);

  k_gru4<<<64, 256, 0, stream>>>(WhhB, b_hh, gib, hx, ysb);

  k_gemm<false, false, true><<<g512, 256, 0, stream>>>(ysb, Wf2T, b_ff2, seq, nullptr, (float*)d_out, 512);
}

// Round 6
// 3008.464 us; speedup vs baseline: 1.7014x; 1.7014x over previous
//
#include <hip/hip_runtime.h>
#include <hip/hip_bf16.h>
#include <stdint.h>

typedef __hip_bfloat16 bf16;
typedef __attribute__((ext_vector_type(8))) short short8;
typedef __attribute__((ext_vector_type(4))) float f32x4;
typedef __attribute__((ext_vector_type(4))) unsigned int u32x4;

#define NN 65536
#define DD 512
#define EE 1048576
#define GG 128
#define LL 512

static __device__ __forceinline__ void gld_lds16(const void* g, void* l) {
  __builtin_amdgcn_global_load_lds((const __attribute__((address_space(1))) uint32_t*)g,
                                   (__attribute__((address_space(3))) uint32_t*)l, 16, 0, 0);
}

// ---------------- prep: transpose/cast weights to bf16 ----------------
__global__ __launch_bounds__(256) void k_prep(
    const float* __restrict__ Wc, const float* __restrict__ Wf1, const float* __restrict__ Wf2,
    const float* __restrict__ Wih, const float* __restrict__ Whh,
    bf16* __restrict__ WcT, bf16* __restrict__ Wf1T, bf16* __restrict__ Wf2T,
    bf16* __restrict__ WihB, bf16* __restrict__ WhhB)
{
  const int i = blockIdx.x * 256 + threadIdx.x;
  if (i < 512 * 512) {
    const int k = i >> 9, n = i & 511;
    WcT [n * 512 + k] = __float2bfloat16(Wc [i]);
    Wf1T[n * 512 + k] = __float2bfloat16(Wf1[i]);
    Wf2T[n * 512 + k] = __float2bfloat16(Wf2[i]);
  }
  if (i < 1536 * 512) {
    WihB[i] = __float2bfloat16(Wih[i]);
    WhhB[i] = __float2bfloat16(Whh[i]);
  }
}

// ---------------- cast node features to bf16 (halves gather volume) ----------------
__global__ __launch_bounds__(256) void k_cast(const float* __restrict__ f, bf16* __restrict__ o) {
  const long i = (long)(blockIdx.x * 256 + threadIdx.x) * 4;
  const float4 v = *(const float4*)&f[i];
  union { bf16 b[4]; ushort4 u; } pk;
  pk.b[0] = __float2bfloat16(v.x);
  pk.b[1] = __float2bfloat16(v.y);
  pk.b[2] = __float2bfloat16(v.z);
  pk.b[3] = __float2bfloat16(v.w);
  *(ushort4*)&o[i] = pk.u;
}

// ---------------- CSR build ----------------
__global__ __launch_bounds__(256) void k_deg(const int* __restrict__ dst, int* __restrict__ deg) {
  const int e = blockIdx.x * 256 + threadIdx.x;
  atomicAdd(&deg[dst[e]], 1);
}

// parallel 3-phase exclusive scan of deg[65536]
__global__ __launch_bounds__(1024) void k_scan1(const int* __restrict__ deg,
                                                int* __restrict__ roff, int* __restrict__ partial) {
  __shared__ int sd[1024];
  const int t = threadIdx.x, b = blockIdx.x, i = b * 1024 + t;
  const int v = deg[i];
  sd[t] = v;
  __syncthreads();
  for (int off = 1; off < 1024; off <<= 1) {
    int add = (t >= off) ? sd[t - off] : 0;
    __syncthreads();
    sd[t] += add;
    __syncthreads();
  }
  roff[i] = sd[t] - v;          // exclusive within chunk
  if (t == 1023) partial[b] = sd[t];
}

__global__ __launch_bounds__(64) void k_scan2(const int* __restrict__ partial, int* __restrict__ base) {
  __shared__ int sd[64];
  const int t = threadIdx.x;
  const int v = partial[t];
  sd[t] = v;
  __syncthreads();
  for (int off = 1; off < 64; off <<= 1) {
    int add = (t >= off) ? sd[t - off] : 0;
    __syncthreads();
    sd[t] += add;
    __syncthreads();
  }
  base[t] = sd[t] - v;
  if (t == 63) base[64] = sd[63];
}

__global__ __launch_bounds__(1024) void k_scan3(const int* __restrict__ base,
                                                int* __restrict__ roff, int* __restrict__ cursor) {
  const int b = blockIdx.x, t = threadIdx.x, i = b * 1024 + t;
  const int v = roff[i] + base[b];
  roff[i] = v;
  cursor[i] = v;
  if (i == 0) roff[NN] = base[64];
}

__global__ __launch_bounds__(256) void k_fill(const int* __restrict__ src, const int* __restrict__ dst,
                                              int* __restrict__ cursor, int* __restrict__ csr) {
  const int e = blockIdx.x * 256 + threadIdx.x;
  const int p = atomicAdd(&cursor[dst[e]], 1);
  csr[p] = src[e];
}

// ---------------- mean aggregation (bf16 gather, fp32 accum) ----------------
__global__ __launch_bounds__(128) void k_agg(
    const bf16* __restrict__ featsb, const int* __restrict__ csr,
    const int* __restrict__ roff, bf16* __restrict__ agg)
{
  const int n = blockIdx.x, t = threadIdx.x;
  const int s0 = roff[n], s1 = roff[n + 1];
  float a0 = 0.f, a1 = 0.f, a2 = 0.f, a3 = 0.f;
  for (int i = s0; i < s1; ++i) {
    const int s = csr[i];
    const ushort4 v = *(const ushort4*)&featsb[(long)s * 512 + t * 4];
    bf16 b0, b1, b2, b3;
    *(uint16_t*)&b0 = v.x; *(uint16_t*)&b1 = v.y;
    *(uint16_t*)&b2 = v.z; *(uint16_t*)&b3 = v.w;
    a0 += __bfloat162float(b0); a1 += __bfloat162float(b1);
    a2 += __bfloat162float(b2); a3 += __bfloat162float(b3);
  }
  const float sc = 1.f / fmaxf((float)(s1 - s0), 1.f);
  union { bf16 b[4]; ushort4 u; } pk;
  pk.b[0] = __float2bfloat16(a0 * sc);
  pk.b[1] = __float2bfloat16(a1 * sc);
  pk.b[2] = __float2bfloat16(a2 * sc);
  pk.b[3] = __float2bfloat16(a3 * sc);
  *(ushort4*)&agg[(long)n * 512 + t * 4] = pk.u;
}

// ---------------- bf16 GEMM: C[M,Ncols] = A[M,512] @ Bt[Ncols,512]^T + bias ----------------
template<bool GATHER, bool RELU, bool SCATTER>
__global__ __launch_bounds__(256) void k_gemm(
    const bf16* __restrict__ A, const bf16* __restrict__ Bt,
    const float* __restrict__ bias, const int* __restrict__ gidx,
    bf16* __restrict__ outb, float* __restrict__ outf, int Ncols)
{
  __shared__ bf16 lsA[128 * 64];
  __shared__ bf16 lsB[128 * 64];
  const int t = threadIdx.x;
  const int lane = t & 63, wid = t >> 6;
  const int wr = wid >> 1, wc = wid & 1;
  const int tm = blockIdx.y * 128, tn = blockIdx.x * 128;
  const int col8 = (t & 7) * 8;
  const int rsub = t >> 3;
  const int lc = lane & 15, lk = lane >> 4;

  long arow[4], brow[4];
#pragma unroll
  for (int i = 0; i < 4; ++i) {
    const int r = tm + i * 32 + rsub;
    int ar = r;
    if constexpr (GATHER) ar = gidx[r];
    arow[i] = (long)ar * 512;
    brow[i] = (long)(tn + i * 32 + rsub) * 512;
  }

  f32x4 acc[4][4];
#pragma unroll
  for (int a = 0; a < 4; ++a)
#pragma unroll
    for (int b = 0; b < 4; ++b) acc[a][b] = (f32x4){0.f, 0.f, 0.f, 0.f};

  for (int ks = 0; ks < 8; ++ks) {
    const int k0 = ks * 64;
#pragma unroll
    for (int i = 0; i < 4; ++i) {
      gld_lds16(A  + arow[i] + k0 + col8, &lsA[i * 2048 + t * 8]);
      gld_lds16(Bt + brow[i] + k0 + col8, &lsB[i * 2048 + t * 8]);
    }
    __syncthreads();
#pragma unroll
    for (int kk = 0; kk < 2; ++kk) {
      short8 af[4], bfr[4];
#pragma unroll
      for (int mi = 0; mi < 4; ++mi)
        af[mi] = *(const short8*)&lsA[(wr * 64 + mi * 16 + lc) * 64 + kk * 32 + lk * 8];
#pragma unroll
      for (int ni = 0; ni < 4; ++ni)
        bfr[ni] = *(const short8*)&lsB[(wc * 64 + ni * 16 + lc) * 64 + kk * 32 + lk * 8];
#pragma unroll
      for (int mi = 0; mi < 4; ++mi)
#pragma unroll
        for (int ni = 0; ni < 4; ++ni)
          acc[mi][ni] = __builtin_amdgcn_mfma_f32_16x16x32_bf16(af[mi], bfr[ni], acc[mi][ni], 0, 0, 0);
    }
    __syncthreads();
  }

  float bv[4];
#pragma unroll
  for (int ni = 0; ni < 4; ++ni) bv[ni] = bias[tn + wc * 64 + ni * 16 + lc];

#pragma unroll
  for (int mi = 0; mi < 4; ++mi) {
    const int r0 = tm + wr * 64 + mi * 16 + lk * 4;
#pragma unroll
    for (int j = 0; j < 4; ++j) {
      const int row = r0 + j;
      long orow;
      if constexpr (SCATTER) orow = (long)gidx[row] * 512;
      else                   orow = (long)row * Ncols;
#pragma unroll
      for (int ni = 0; ni < 4; ++ni) {
        float v = acc[mi][ni][j] + bv[ni];
        if constexpr (RELU) v = fmaxf(v, 0.f);
        const int c = tn + wc * 64 + ni * 16 + lc;
        if constexpr (SCATTER) outf[orow + c] = v;
        else                   outb[orow + c] = __float2bfloat16(v);
      }
    }
  }
}

// ---------------- persistent GRU v5 ----------------
// 128 blocks = 8 chains x 16 col-slices (32 cols); 2 waves/block, wave w owns
// 16 output cols. W slice (3 gates x 32 cols x 512) in LDS (97.5 KB, 520-pad).
// Exchange: packed-bf16 hx[2][chain][16g][512d] (256 KB, IF-resident, lines
// reused every 2 steps -> no write-allocate HBM fetches, shallow drain).
// Producer: 4 h short-stores (sc0 sc1) -> 4 ys nt stores -> s_waitcnt vmcnt(4)
// (issue-order counting: waits only the h stores) -> relaxed-agent stamp.
// Consumer: poll 32 stamps (one 128B line), then 16 pipelined dwordx4 sc0 sc1
// loads that ARE the MFMA A-fragments (no unpack). No intra-block barriers in
// steady state. gi raw loads issued before the poll; covered by load vmcnt(0).
__global__ __launch_bounds__(128, 1) void k_gru5(
    const bf16* __restrict__ Whh, const float* __restrict__ bhh,
    const bf16* __restrict__ gi, bf16* __restrict__ hx,
    bf16* __restrict__ ys, int* __restrict__ flags)
{
  __shared__ bf16 lsW[96 * 520];
  const int t = threadIdx.x, lane = t & 63, w = t >> 6;
  const int chain = blockIdx.x >> 4, jcb = blockIdx.x & 15;
  const int lc = lane & 15, lk = lane >> 4;
  const int g0 = chain * 16;
  const int cols0 = jcb * 32;
  const int d = cols0 + w * 16 + lc;

  // stage W slice: local row = gate*32 + rr  ->  W_hh row gate*512 + cols0 + rr
#pragma unroll
  for (int it = 0; it < 48; ++it) {
    const int c = it * 128 + t;
    const int row = c >> 6, col8 = (c & 63) * 8;
    const int e = ((row >> 5) << 9) + cols0 + (row & 31);
    *(uint4*)&lsW[row * 520 + col8] = *(const uint4*)&Whh[(long)e * 512 + col8];
  }
  __syncthreads();

  const float bR = bhh[d], bZ = bhh[512 + d], bN = bhh[1024 + d];
  float hreg[4] = {0.f, 0.f, 0.f, 0.f};

  // consumer A-frag base: hx[parity][chain][lc][lk*8]; kk advances 32 bf16 = 64B
  const bf16* pb0 = hx + chain * 8192 + lc * 512 + lk * 8;
  const bf16* gp[4];
  long ysb4[4];
  int hsb[4];
#pragma unroll
  for (int j = 0; j < 4; ++j) {
    const int gl = lk * 4 + j;                 // local group 0..15
    const int g = g0 + gl;
    gp[j]   = gi + (long)g * 786432 + d;       // g*512*1536
    ysb4[j] = ((long)g << 18) + d;             // g*512*512
    hsb[j]  = chain * 8192 + gl * 512 + d;     // hx offset (parity added later)
  }
  int* chflags = flags + chain * 32;
  int* myflag  = chflags + jcb * 2 + w;

  for (int l = 0; l < 512; ++l) {
    // gi raw loads (plain cached); the consumer vmcnt(0) covers their latency
    uint32_t gr[12];
#pragma unroll
    for (int j = 0; j < 4; ++j) {
      asm volatile("global_load_ushort %0, %1, off"             : "=v"(gr[j * 3 + 0]) : "v"(gp[j]) : "memory");
      asm volatile("global_load_ushort %0, %1, off offset:1024" : "=v"(gr[j * 3 + 1]) : "v"(gp[j]) : "memory");
      asm volatile("global_load_ushort %0, %1, off offset:2048" : "=v"(gr[j * 3 + 2]) : "v"(gp[j]) : "memory");
      gp[j] += 1536;
    }

    f32x4 acc[3] = { (f32x4){0.f,0.f,0.f,0.f}, (f32x4){0.f,0.f,0.f,0.f}, (f32x4){0.f,0.f,0.f,0.f} };
    if (l > 0) {
      // wait for all 32 producers of this chain to stamp step l (one 128B line)
      int ok;
      do {
        const int v = __hip_atomic_load(&chflags[lane & 31], __ATOMIC_RELAXED,
                                        __HIP_MEMORY_SCOPE_AGENT);
        ok = __all(v >= l);
      } while (!ok);
      asm volatile("" ::: "memory");

      // h_{l-1} from hx[(l-1)&1]: 16 pipelined coherent loads = A-frags direct
      const bf16* pb = pb0 + (((l - 1) & 1) << 16);
      u32x4 hv[16];
#pragma unroll
      for (int kk = 0; kk < 16; ++kk)
        asm volatile("global_load_dwordx4 %0, %1, off offset:%2 sc0 sc1"
                     : "=v"(hv[kk]) : "v"(pb), "n"(kk * 64) : "memory");
      asm volatile("s_waitcnt vmcnt(0)" ::: "memory");
      __builtin_amdgcn_sched_barrier(0);

#pragma unroll
      for (int kk = 0; kk < 16; ++kk) {
        union { u32x4 u; short8 s; } cv;
        cv.u = hv[kk];
#pragma unroll
        for (int gate = 0; gate < 3; ++gate) {
          const short8 bfr = *(const short8*)&lsW[(gate * 32 + w * 16 + lc) * 520 + kk * 32 + lk * 8];
          acc[gate] = __builtin_amdgcn_mfma_f32_16x16x32_bf16(cv.s, bfr, acc[gate], 0, 0, 0);
        }
      }
    } else {
      asm volatile("s_waitcnt vmcnt(0)" ::: "memory");
      __builtin_amdgcn_sched_barrier(0);
    }

    // gates; then h stores FIRST, ys nt after, vmcnt(4) waits only the h stores
    bf16* hw = hx + ((l & 1) << 16);
    uint32_t hbits[4];
#pragma unroll
    for (int j = 0; j < 4; ++j) {
      union { uint32_t u; float f; } cu;
      cu.u = gr[j * 3 + 0] << 16;  const float giR = cu.f;
      cu.u = gr[j * 3 + 1] << 16;  const float giZ = cu.f;
      cu.u = gr[j * 3 + 2] << 16;  const float giN = cu.f;
      const float r = 1.f / (1.f + __expf(-(giR + acc[0][j] + bR)));
      const float z = 1.f / (1.f + __expf(-(giZ + acc[1][j] + bZ)));
      const float x2 = giN + r * (acc[2][j] + bN);
      const float ex = __expf(2.f * x2);
      const float n = 1.f - 2.f / (ex + 1.f);          // tanh
      const float hn = (1.f - z) * n + z * hreg[j];
      hreg[j] = hn;
      const bf16 hnb = __float2bfloat16(hn);
      hbits[j] = (uint32_t)(*(const uint16_t*)&hnb);
      asm volatile("global_store_short %0, %1, off sc0 sc1"
                   :: "v"(hw + hsb[j]), "v"(hbits[j]) : "memory");
    }
#pragma unroll
    for (int j = 0; j < 4; ++j)
      asm volatile("global_store_short %0, %1, off nt"
                   :: "v"(ys + ysb4[j] + ((long)l << 9)), "v"(hbits[j]) : "memory");
    asm volatile("s_waitcnt vmcnt(4)" ::: "memory");    // h stores (oldest 4) done
    if (lane == 0)
      __hip_atomic_store(myflag, l + 1, __ATOMIC_RELAXED, __HIP_MEMORY_SCOPE_AGENT);
  }
}

// ---------------- launch ----------------
extern "C" void kernel_launch(void* const* d_in, const int* in_sizes, int n_in,
                              void* d_out, int out_size, void* d_ws, size_t ws_size,
                              hipStream_t stream)
{
  (void)in_sizes; (void)n_in; (void)out_size; (void)ws_size;
  const float* in_feats = (const float*)d_in[0];
  const int*   e_src    = (const int*)d_in[1];
  const int*   e_dst    = (const int*)d_in[2];
  const int*   seq      = (const int*)d_in[3];
  const float* W_conv   = (const float*)d_in[4];
  const float* b_conv   = (const float*)d_in[5];
  const float* W_ff1    = (const float*)d_in[6];
  const float* b_ff1    = (const float*)d_in[7];
  const float* W_ih     = (const float*)d_in[8];
  const float* W_hh     = (const float*)d_in[9];
  const float* b_ih     = (const float*)d_in[10];
  const float* b_hh     = (const float*)d_in[11];
  const float* W_ff2    = (const float*)d_in[12];
  const float* b_ff2    = (const float*)d_in[13];

  uint8_t* ws = (uint8_t*)d_ws;
  int*  deg     = (int*) (ws + 0);
  int*  cursor  = (int*) (ws + 262144u);
  int*  roff    = (int*) (ws + 524288u);
  bf16* WcT     = (bf16*)(ws + 1048576u);
  bf16* Wf1T    = (bf16*)(ws + 1572864u);
  bf16* Wf2T    = (bf16*)(ws + 2097152u);
  bf16* WihB    = (bf16*)(ws + 2621440u);
  bf16* WhhB    = (bf16*)(ws + 4194304u);
  int*  csr     = (int*) (ws + 6291456u);
  int*  flags   = (int*) (ws + 10485760u);     // 8*32 ints (monotonic stamps)
  int*  partial = (int*) (ws + 10616832u);     // 64 ints
  int*  sbase   = (int*) (ws + 10620928u);     // 65 ints
  bf16* hx      = (bf16*)(ws + 11534336u);     // 2*8*16*512 bf16 = 256 KB exchange
  bf16* med2    = (bf16*)(ws + 16777216u);     // 67MB; reused as ys after gi GEMM
  bf16* ysb     = med2;
  bf16* gib     = (bf16*)(ws + 83886080u);     // 201MB; aggb/med1/featsb live here pre-gi
  bf16* aggb    = (bf16*)(ws + 83886080u);
  bf16* med1    = (bf16*)(ws + 150994944u);    // also featsb (dead before med1 written)
  bf16* featsb  = (bf16*)(ws + 150994944u);

  hipMemsetAsync(deg,   0, NN * 4,     stream);
  hipMemsetAsync(flags, 0, 8 * 32 * 4, stream);

  k_prep <<<3072, 256, 0, stream>>>(W_conv, W_ff1, W_ff2, W_ih, W_hh, WcT, Wf1T, Wf2T, WihB, WhhB);
  k_cast <<<NN * DD / 1024, 256, 0, stream>>>(in_feats, featsb);
  k_deg  <<<EE / 256, 256, 0, stream>>>(e_dst, deg);
  k_scan1<<<64, 1024, 0, stream>>>(deg, roff, partial);
  k_scan2<<<1, 64, 0, stream>>>(partial, sbase);
  k_scan3<<<64, 1024, 0, stream>>>(sbase, roff, cursor);
  k_fill <<<EE / 256, 256, 0, stream>>>(e_src, e_dst, cursor, csr);
  k_agg  <<<NN, 128, 0, stream>>>(featsb, csr, roff, aggb);

  dim3 g512(4, 512), g1536(12, 512);
  k_gemm<false, false, false><<<g512,  256, 0, stream>>>(aggb, WcT,  b_conv, nullptr, med1, nullptr, 512);
  k_gemm<false, true,  false><<<g512,  256, 0, stream>>>(med1, Wf1T, b_ff1,  nullptr, med2, nullptr, 512);
  k_gemm<true,  false, false><<<g1536, 256, 0, stream>>>(med2, WihB, b_ih,   seq,     gib,  nullptr, 1536);

  k_gru5<<<128, 128, 0, stream>>>(WhhB, b_hh, gib, hx, ysb, flags);

  k_gemm<false, false, true><<<g512, 256, 0, stream>>>(ysb, Wf2T, b_ff2, seq, nullptr, (float*)d_out, 512);
}

// Round 8
// 2539.819 us; speedup vs baseline: 2.0153x; 1.1845x over previous
//
#include <hip/hip_runtime.h>
#include <hip/hip_bf16.h>
#include <stdint.h>

typedef __hip_bfloat16 bf16;
typedef __attribute__((ext_vector_type(8))) short short8;
typedef __attribute__((ext_vector_type(4))) float f32x4;
typedef __attribute__((ext_vector_type(4))) unsigned int u32x4;
typedef __attribute__((ext_vector_type(2))) unsigned int u32x2;

#define NN 65536
#define DD 512
#define EE 1048576
#define GG 128
#define LL 512

static __device__ __forceinline__ void gld_lds16(const void* g, void* l) {
  __builtin_amdgcn_global_load_lds((const __attribute__((address_space(1))) uint32_t*)g,
                                   (__attribute__((address_space(3))) uint32_t*)l, 16, 0, 0);
}

// ---------------- prep: transpose/cast weights to bf16 ----------------
__global__ __launch_bounds__(256) void k_prep(
    const float* __restrict__ Wc, const float* __restrict__ Wf1, const float* __restrict__ Wf2,
    const float* __restrict__ Wih, const float* __restrict__ Whh,
    bf16* __restrict__ WcT, bf16* __restrict__ Wf1T, bf16* __restrict__ Wf2T,
    bf16* __restrict__ WihB, bf16* __restrict__ WhhB)
{
  const int i = blockIdx.x * 256 + threadIdx.x;
  if (i < 512 * 512) {
    const int k = i >> 9, n = i & 511;
    WcT [n * 512 + k] = __float2bfloat16(Wc [i]);
    Wf1T[n * 512 + k] = __float2bfloat16(Wf1[i]);
    Wf2T[n * 512 + k] = __float2bfloat16(Wf2[i]);
  }
  if (i < 1536 * 512) {
    WihB[i] = __float2bfloat16(Wih[i]);
    WhhB[i] = __float2bfloat16(Whh[i]);
  }
}

// ---------------- cast node features to bf16 (halves gather volume) ----------------
__global__ __launch_bounds__(256) void k_cast(const float* __restrict__ f, bf16* __restrict__ o) {
  const long i = (long)(blockIdx.x * 256 + threadIdx.x) * 4;
  const float4 v = *(const float4*)&f[i];
  union { bf16 b[4]; ushort4 u; } pk;
  pk.b[0] = __float2bfloat16(v.x);
  pk.b[1] = __float2bfloat16(v.y);
  pk.b[2] = __float2bfloat16(v.z);
  pk.b[3] = __float2bfloat16(v.w);
  *(ushort4*)&o[i] = pk.u;
}

// ---------------- CSR build ----------------
__global__ __launch_bounds__(256) void k_deg(const int* __restrict__ dst, int* __restrict__ deg) {
  const int e = blockIdx.x * 256 + threadIdx.x;
  atomicAdd(&deg[dst[e]], 1);
}

// parallel 3-phase exclusive scan of deg[65536]
__global__ __launch_bounds__(1024) void k_scan1(const int* __restrict__ deg,
                                                int* __restrict__ roff, int* __restrict__ partial) {
  __shared__ int sd[1024];
  const int t = threadIdx.x, b = blockIdx.x, i = b * 1024 + t;
  const int v = deg[i];
  sd[t] = v;
  __syncthreads();
  for (int off = 1; off < 1024; off <<= 1) {
    int add = (t >= off) ? sd[t - off] : 0;
    __syncthreads();
    sd[t] += add;
    __syncthreads();
  }
  roff[i] = sd[t] - v;          // exclusive within chunk
  if (t == 1023) partial[b] = sd[t];
}

__global__ __launch_bounds__(64) void k_scan2(const int* __restrict__ partial, int* __restrict__ base) {
  __shared__ int sd[64];
  const int t = threadIdx.x;
  const int v = partial[t];
  sd[t] = v;
  __syncthreads();
  for (int off = 1; off < 64; off <<= 1) {
    int add = (t >= off) ? sd[t - off] : 0;
    __syncthreads();
    sd[t] += add;
    __syncthreads();
  }
  base[t] = sd[t] - v;
  if (t == 63) base[64] = sd[63];
}

__global__ __launch_bounds__(1024) void k_scan3(const int* __restrict__ base,
                                                int* __restrict__ roff, int* __restrict__ cursor) {
  const int b = blockIdx.x, t = threadIdx.x, i = b * 1024 + t;
  const int v = roff[i] + base[b];
  roff[i] = v;
  cursor[i] = v;
  if (i == 0) roff[NN] = base[64];
}

__global__ __launch_bounds__(256) void k_fill(const int* __restrict__ src, const int* __restrict__ dst,
                                              int* __restrict__ cursor, int* __restrict__ csr) {
  const int e = blockIdx.x * 256 + threadIdx.x;
  const int p = atomicAdd(&cursor[dst[e]], 1);
  csr[p] = src[e];
}

// ---------------- mean aggregation (bf16 gather, fp32 accum) ----------------
__global__ __launch_bounds__(128) void k_agg(
    const bf16* __restrict__ featsb, const int* __restrict__ csr,
    const int* __restrict__ roff, bf16* __restrict__ agg)
{
  const int n = blockIdx.x, t = threadIdx.x;
  const int s0 = roff[n], s1 = roff[n + 1];
  float a0 = 0.f, a1 = 0.f, a2 = 0.f, a3 = 0.f;
  for (int i = s0; i < s1; ++i) {
    const int s = csr[i];
    const ushort4 v = *(const ushort4*)&featsb[(long)s * 512 + t * 4];
    bf16 b0, b1, b2, b3;
    *(uint16_t*)&b0 = v.x; *(uint16_t*)&b1 = v.y;
    *(uint16_t*)&b2 = v.z; *(uint16_t*)&b3 = v.w;
    a0 += __bfloat162float(b0); a1 += __bfloat162float(b1);
    a2 += __bfloat162float(b2); a3 += __bfloat162float(b3);
  }
  const float sc = 1.f / fmaxf((float)(s1 - s0), 1.f);
  union { bf16 b[4]; ushort4 u; } pk;
  pk.b[0] = __float2bfloat16(a0 * sc);
  pk.b[1] = __float2bfloat16(a1 * sc);
  pk.b[2] = __float2bfloat16(a2 * sc);
  pk.b[3] = __float2bfloat16(a3 * sc);
  *(ushort4*)&agg[(long)n * 512 + t * 4] = pk.u;
}

// ---------------- bf16 GEMM: C[M,Ncols] = A[M,512] @ Bt[Ncols,512]^T + bias ----------------
template<bool GATHER, bool RELU>
__global__ __launch_bounds__(256) void k_gemm(
    const bf16* __restrict__ A, const bf16* __restrict__ Bt,
    const float* __restrict__ bias, const int* __restrict__ gidx,
    bf16* __restrict__ outb, int Ncols)
{
  __shared__ bf16 lsA[128 * 64];
  __shared__ bf16 lsB[128 * 64];
  const int t = threadIdx.x;
  const int lane = t & 63, wid = t >> 6;
  const int wr = wid >> 1, wc = wid & 1;
  const int tm = blockIdx.y * 128, tn = blockIdx.x * 128;
  const int col8 = (t & 7) * 8;
  const int rsub = t >> 3;
  const int lc = lane & 15, lk = lane >> 4;

  long arow[4], brow[4];
#pragma unroll
  for (int i = 0; i < 4; ++i) {
    const int r = tm + i * 32 + rsub;
    int ar = r;
    if constexpr (GATHER) ar = gidx[r];
    arow[i] = (long)ar * 512;
    brow[i] = (long)(tn + i * 32 + rsub) * 512;
  }

  f32x4 acc[4][4];
#pragma unroll
  for (int a = 0; a < 4; ++a)
#pragma unroll
    for (int b = 0; b < 4; ++b) acc[a][b] = (f32x4){0.f, 0.f, 0.f, 0.f};

  for (int ks = 0; ks < 8; ++ks) {
    const int k0 = ks * 64;
#pragma unroll
    for (int i = 0; i < 4; ++i) {
      gld_lds16(A  + arow[i] + k0 + col8, &lsA[i * 2048 + t * 8]);
      gld_lds16(Bt + brow[i] + k0 + col8, &lsB[i * 2048 + t * 8]);
    }
    __syncthreads();
#pragma unroll
    for (int kk = 0; kk < 2; ++kk) {
      short8 af[4], bfr[4];
#pragma unroll
      for (int mi = 0; mi < 4; ++mi)
        af[mi] = *(const short8*)&lsA[(wr * 64 + mi * 16 + lc) * 64 + kk * 32 + lk * 8];
#pragma unroll
      for (int ni = 0; ni < 4; ++ni)
        bfr[ni] = *(const short8*)&lsB[(wc * 64 + ni * 16 + lc) * 64 + kk * 32 + lk * 8];
#pragma unroll
      for (int mi = 0; mi < 4; ++mi)
#pragma unroll
        for (int ni = 0; ni < 4; ++ni)
          acc[mi][ni] = __builtin_amdgcn_mfma_f32_16x16x32_bf16(af[mi], bfr[ni], acc[mi][ni], 0, 0, 0);
    }
    __syncthreads();
  }

  float bv[4];
#pragma unroll
  for (int ni = 0; ni < 4; ++ni) bv[ni] = bias[tn + wc * 64 + ni * 16 + lc];

#pragma unroll
  for (int mi = 0; mi < 4; ++mi) {
    const int r0 = tm + wr * 64 + mi * 16 + lk * 4;
#pragma unroll
    for (int j = 0; j < 4; ++j) {
      const int row = r0 + j;
      const long orow = (long)row * Ncols;
#pragma unroll
      for (int ni = 0; ni < 4; ++ni) {
        float v = acc[mi][ni][j] + bv[ni];
        if constexpr (RELU) v = fmaxf(v, 0.f);
        const int c = tn + wc * 64 + ni * 16 + lc;
        outb[orow + c] = __float2bfloat16(v);
      }
    }
  }
}

// ---------------- ff2 GEMM reading ys2 layout, scatter output ----------------
// ys2 element (g,l,k):  byte = ((l*8 + (g>>4))*32 + (k>>4))*512 + (g&15)*32 + (k&15)*2
__global__ __launch_bounds__(256) void k_gemm_ys(
    const uint8_t* __restrict__ Ay, const bf16* __restrict__ Bt,
    const float* __restrict__ bias, const int* __restrict__ gidx,
    float* __restrict__ outf)
{
  __shared__ bf16 lsA[128 * 64];
  __shared__ bf16 lsB[128 * 64];
  const int t = threadIdx.x;
  const int lane = t & 63, wid = t >> 6;
  const int wr = wid >> 1, wc = wid & 1;
  const int tm = blockIdx.y * 128, tn = blockIdx.x * 128;
  const int col8 = (t & 7) * 8;
  const int rsub = t >> 3;
  const int lc = lane & 15, lk = lane >> 4;

  long arow[4], brow[4];
#pragma unroll
  for (int i = 0; i < 4; ++i) {
    const int r = tm + i * 32 + rsub;
    const int g = r >> 9, l = r & 511;
    arow[i] = ((long)l * 8 + (g >> 4)) * 16384 + (g & 15) * 32;
    brow[i] = (long)(tn + i * 32 + rsub) * 512;
  }

  f32x4 acc[4][4];
#pragma unroll
  for (int a = 0; a < 4; ++a)
#pragma unroll
    for (int b = 0; b < 4; ++b) acc[a][b] = (f32x4){0.f, 0.f, 0.f, 0.f};

  for (int ks = 0; ks < 8; ++ks) {
    const int k0 = ks * 64;
    const int kk16 = k0 + col8;
    const long aoff = ((long)(kk16 >> 4) << 9) + ((kk16 & 15) << 1);
#pragma unroll
    for (int i = 0; i < 4; ++i) {
      gld_lds16(Ay + arow[i] + aoff, &lsA[i * 2048 + t * 8]);
      gld_lds16(Bt + brow[i] + k0 + col8, &lsB[i * 2048 + t * 8]);
    }
    __syncthreads();
#pragma unroll
    for (int kk = 0; kk < 2; ++kk) {
      short8 af[4], bfr[4];
#pragma unroll
      for (int mi = 0; mi < 4; ++mi)
        af[mi] = *(const short8*)&lsA[(wr * 64 + mi * 16 + lc) * 64 + kk * 32 + lk * 8];
#pragma unroll
      for (int ni = 0; ni < 4; ++ni)
        bfr[ni] = *(const short8*)&lsB[(wc * 64 + ni * 16 + lc) * 64 + kk * 32 + lk * 8];
#pragma unroll
      for (int mi = 0; mi < 4; ++mi)
#pragma unroll
        for (int ni = 0; ni < 4; ++ni)
          acc[mi][ni] = __builtin_amdgcn_mfma_f32_16x16x32_bf16(af[mi], bfr[ni], acc[mi][ni], 0, 0, 0);
    }
    __syncthreads();
  }

  float bv[4];
#pragma unroll
  for (int ni = 0; ni < 4; ++ni) bv[ni] = bias[tn + wc * 64 + ni * 16 + lc];

#pragma unroll
  for (int mi = 0; mi < 4; ++mi) {
    const int r0 = tm + wr * 64 + mi * 16 + lk * 4;
#pragma unroll
    for (int j = 0; j < 4; ++j) {
      const int row = r0 + j;
      const long orow = (long)gidx[row] * 512;
#pragma unroll
      for (int ni = 0; ni < 4; ++ni) {
        const int c = tn + wc * 64 + ni * 16 + lc;
        outf[orow + c] = acc[mi][ni][j] + bv[ni];
      }
    }
  }
}

// ---------------- persistent GRU v7: operand-swapped MFMA, single-stream exchange ----
// 128 blocks = 8 chains x 16 jcb; 2 waves/block; wave p = jcb*2+w owns 16 d-cols
// for all 16 groups of its chain. MFMA operands SWAPPED vs v5 (A = W rows=d,
// B = h cols=groups) so each lane produces 4 CONSECUTIVE d for one group ->
// the per-step h output is ONE dwordx2 per lane, and a wave's 64 lanes write
// 8 FULL 64B lines (write-combine, no write-allocate fetch). ys2[l][chain]
// [p][gl][16dl] is simultaneously the exchange buffer AND the ys history
// consumed by k_gemm_ys -> the ys store stream (and its HBM acks inside the
// poll's vmcnt(0)) is gone. Sync protocol = r6-proven: h stores sc0 sc1,
// vmcnt(0) drain (1 store), agent-relaxed stamp; consumer polls 32 stamps then
// 16 pipelined dwordx4 sc0 sc1 loads that are the MFMA B-fragments directly.
__global__ __launch_bounds__(128, 1) void k_gru7(
    const bf16* __restrict__ Whh, const float* __restrict__ bhh,
    const bf16* __restrict__ gi, uint8_t* __restrict__ ys2, int* __restrict__ flags)
{
  __shared__ bf16 lsW[96 * 520];
  const int t = threadIdx.x, lane = t & 63, w = t >> 6;
  const int chain = blockIdx.x >> 4, jcb = blockIdx.x & 15;
  const int lc = lane & 15, lk = lane >> 4;
  const int g0 = chain * 16;
  const int cols0 = jcb * 32;
  const int p = jcb * 2 + w;            // producer / d-tile index 0..31
  const int d0 = p * 16 + lk * 4;       // this lane's 4 consecutive d (group lc)

  // stage W slice: rows gate*32+rr -> Whh[gate*512 + cols0 + rr] (v5-proven layout)
#pragma unroll
  for (int it = 0; it < 48; ++it) {
    const int c = it * 128 + t;
    const int row = c >> 6, col8 = (c & 63) * 8;
    const int e = ((row >> 5) << 9) + cols0 + (row & 31);
    *(uint4*)&lsW[row * 520 + col8] = *(const uint4*)&Whh[(long)e * 512 + col8];
  }
  __syncthreads();

  float bRa[4], bZa[4], bNa[4];
#pragma unroll
  for (int j = 0; j < 4; ++j) {
    bRa[j] = bhh[d0 + j];
    bZa[j] = bhh[512 + d0 + j];
    bNa[j] = bhh[1024 + d0 + j];
  }
  float hreg[4] = {0.f, 0.f, 0.f, 0.f};

  // gi: lane covers (group g0+lc, gates at +0/+512/+1024, d = d0..d0+3)
  const bf16* gp = gi + (long)(g0 + lc) * 786432 + d0;
  // producer store base (bytes): [l][chain][p][gl=lc][dl=lk*4]
  uint8_t* psto = ys2 + (long)chain * 16384 + p * 512 + lc * 32 + lk * 8;
  // consumer lane offset (bytes) within a (l,chain) slab
  const long laneoff = (long)(lk >> 1) * 512 + lc * 32 + (lk & 1) * 16;

  int* chflags = flags + chain * 32;
  int* myflag  = chflags + p;

  for (int l = 0; l < 512; ++l) {
    // gi dwordx2 loads (3 gates x 4 consecutive d); drained before gates
    u32x2 gRv, gZv, gNv;
    asm volatile("global_load_dwordx2 %0, %1, off"             : "=v"(gRv) : "v"(gp) : "memory");
    asm volatile("global_load_dwordx2 %0, %1, off offset:1024" : "=v"(gZv) : "v"(gp) : "memory");
    asm volatile("global_load_dwordx2 %0, %1, off offset:2048" : "=v"(gNv) : "v"(gp) : "memory");
    gp += 1536;

    f32x4 acc[3] = { (f32x4){0.f,0.f,0.f,0.f}, (f32x4){0.f,0.f,0.f,0.f}, (f32x4){0.f,0.f,0.f,0.f} };
    if (l > 0) {
      // wait for all 32 producers of this chain to stamp step l
      int ok;
      do {
        const int v = __hip_atomic_load(&chflags[lane & 31], __ATOMIC_RELAXED,
                                        __HIP_MEMORY_SCOPE_AGENT);
        ok = __all(v >= l);
      } while (!ok);
      asm volatile("" ::: "memory");

      // B-frags: h_{l-1}[group lc][k = kk*32+lk*8 ..+8] = 16 pipelined 16B loads
      const uint8_t* pb = ys2 + ((long)(l - 1) * 8 + chain) * 16384 + laneoff;
      u32x4 hv[16];
#pragma unroll
      for (int q = 0; q < 4; ++q) {
        const uint8_t* pbq = pb + q * 4096;
#pragma unroll
        for (int r2 = 0; r2 < 4; ++r2)
          asm volatile("global_load_dwordx4 %0, %1, off offset:%2 sc0 sc1"
                       : "=v"(hv[q * 4 + r2]) : "v"(pbq), "n"(r2 * 1024) : "memory");
      }
      asm volatile("s_waitcnt vmcnt(0)" ::: "memory");
      __builtin_amdgcn_sched_barrier(0);

#pragma unroll
      for (int kk = 0; kk < 16; ++kk) {
        union { u32x4 u; short8 s; } cv;
        cv.u = hv[kk];
#pragma unroll
        for (int gate = 0; gate < 3; ++gate) {
          const short8 wfr = *(const short8*)&lsW[(gate * 32 + w * 16 + lc) * 520 + kk * 32 + lk * 8];
          // A = W (rows = d), B = h (cols = groups): D[row=d0+j][col=group lc]
          acc[gate] = __builtin_amdgcn_mfma_f32_16x16x32_bf16(wfr, cv.s, acc[gate], 0, 0, 0);
        }
      }
    } else {
      asm volatile("s_waitcnt vmcnt(0)" ::: "memory");
      __builtin_amdgcn_sched_barrier(0);
    }

    uint32_t hb[4];
#pragma unroll
    for (int j = 0; j < 4; ++j) {
      const uint32_t sh = (j & 1) * 16;
      union { uint32_t u; float f; } cR, cZ, cN;
      cR.u = ((gRv[j >> 1] >> sh) & 0xffffu) << 16;
      cZ.u = ((gZv[j >> 1] >> sh) & 0xffffu) << 16;
      cN.u = ((gNv[j >> 1] >> sh) & 0xffffu) << 16;
      const float r = 1.f / (1.f + __expf(-(cR.f + acc[0][j] + bRa[j])));
      const float z = 1.f / (1.f + __expf(-(cZ.f + acc[1][j] + bZa[j])));
      const float x2 = cN.f + r * (acc[2][j] + bNa[j]);
      const float ex = __expf(2.f * x2);
      const float n = 1.f - 2.f / (ex + 1.f);          // tanh
      const float hn = (1.f - z) * n + z * hreg[j];
      hreg[j] = hn;
      const bf16 hnb = __float2bfloat16(hn);
      hb[j] = (uint32_t)(*(const uint16_t*)&hnb);
    }
    u32x2 hp;
    hp[0] = hb[0] | (hb[1] << 16);
    hp[1] = hb[2] | (hb[3] << 16);
    asm volatile("global_store_dwordx2 %0, %1, off sc0 sc1" :: "v"(psto), "v"(hp) : "memory");
    psto += 131072;                                     // next l-slab (8*16384 B)
    asm volatile("s_waitcnt vmcnt(0)" ::: "memory");    // drain the single h store
    if (lane == 0)
      __hip_atomic_store(myflag, l + 1, __ATOMIC_RELAXED, __HIP_MEMORY_SCOPE_AGENT);
  }
}

// ---------------- launch ----------------
extern "C" void kernel_launch(void* const* d_in, const int* in_sizes, int n_in,
                              void* d_out, int out_size, void* d_ws, size_t ws_size,
                              hipStream_t stream)
{
  (void)in_sizes; (void)n_in; (void)out_size; (void)ws_size;
  const float* in_feats = (const float*)d_in[0];
  const int*   e_src    = (const int*)d_in[1];
  const int*   e_dst    = (const int*)d_in[2];
  const int*   seq      = (const int*)d_in[3];
  const float* W_conv   = (const float*)d_in[4];
  const float* b_conv   = (const float*)d_in[5];
  const float* W_ff1    = (const float*)d_in[6];
  const float* b_ff1    = (const float*)d_in[7];
  const float* W_ih     = (const float*)d_in[8];
  const float* W_hh     = (const float*)d_in[9];
  const float* b_ih     = (const float*)d_in[10];
  const float* b_hh     = (const float*)d_in[11];
  const float* W_ff2    = (const float*)d_in[12];
  const float* b_ff2    = (const float*)d_in[13];

  uint8_t* ws = (uint8_t*)d_ws;
  int*  deg     = (int*) (ws + 0);
  int*  cursor  = (int*) (ws + 262144u);
  int*  roff    = (int*) (ws + 524288u);
  bf16* WcT     = (bf16*)(ws + 1048576u);
  bf16* Wf1T    = (bf16*)(ws + 1572864u);
  bf16* Wf2T    = (bf16*)(ws + 2097152u);
  bf16* WihB    = (bf16*)(ws + 2621440u);
  bf16* WhhB    = (bf16*)(ws + 4194304u);
  int*  csr     = (int*) (ws + 6291456u);
  int*  flags   = (int*) (ws + 10485760u);     // 8*32 ints (monotonic stamps)
  int*  partial = (int*) (ws + 10616832u);     // 64 ints
  int*  sbase   = (int*) (ws + 10620928u);     // 65 ints
  bf16* med2    = (bf16*)(ws + 16777216u);     // 67MB; reused as ys2 after gi GEMM
  uint8_t* ys2  = (uint8_t*)med2;              // [l][chain][p][gl][16dl] bf16 = 64MB
  bf16* gib     = (bf16*)(ws + 83886080u);     // 201MB; aggb/med1/featsb live here pre-gi
  bf16* aggb    = (bf16*)(ws + 83886080u);
  bf16* med1    = (bf16*)(ws + 150994944u);    // also featsb (dead before med1 written)
  bf16* featsb  = (bf16*)(ws + 150994944u);

  hipMemsetAsync(deg,   0, NN * 4,     stream);
  hipMemsetAsync(flags, 0, 8 * 32 * 4, stream);

  k_prep <<<3072, 256, 0, stream>>>(W_conv, W_ff1, W_ff2, W_ih, W_hh, WcT, Wf1T, Wf2T, WihB, WhhB);
  k_cast <<<NN * DD / 1024, 256, 0, stream>>>(in_feats, featsb);
  k_deg  <<<EE / 256, 256, 0, stream>>>(e_dst, deg);
  k_scan1<<<64, 1024, 0, stream>>>(deg, roff, partial);
  k_scan2<<<1, 64, 0, stream>>>(partial, sbase);
  k_scan3<<<64, 1024, 0, stream>>>(sbase, roff, cursor);
  k_fill <<<EE / 256, 256, 0, stream>>>(e_src, e_dst, cursor, csr);
  k_agg  <<<NN, 128, 0, stream>>>(featsb, csr, roff, aggb);

  dim3 g512(4, 512), g1536(12, 512);
  k_gemm<false, false><<<g512,  256, 0, stream>>>(aggb, WcT,  b_conv, nullptr, med1, 512);
  k_gemm<false, true ><<<g512,  256, 0, stream>>>(med1, Wf1T, b_ff1,  nullptr, med2, 512);
  k_gemm<true,  false><<<g1536, 256, 0, stream>>>(med2, WihB, b_ih,   seq,     gib,  1536);

  k_gru7<<<128, 128, 0, stream>>>(WhhB, b_hh, gib, ys2, flags);

  k_gemm_ys<<<g512, 256, 0, stream>>>(ys2, Wf2T, b_ff2, seq, (float*)d_out);
}